// Round 1
// baseline (227.899 us; speedup 1.0000x reference)
//
#include <hip/hip_runtime.h>

#define D 4096

// In-register 16-point Walsh-Hadamard (natural order butterflies).
__device__ __forceinline__ void fwht16(float v[16]) {
#pragma unroll
    for (int s = 1; s < 16; s <<= 1) {
#pragma unroll
        for (int i = 0; i < 16; i++) {
            if (!(i & s)) {
                float a = v[i], b = v[i ^ s];
                v[i]     = a + b;
                v[i ^ s] = a - b;
            }
        }
    }
}

// One block per row. 256 threads x 16 floats = 4096 elements in registers.
// H_4096 = H16(high bits a2) (x) H16(mid bits a1) (x) H16(low bits b).
// LDS layout padded +1 float per 16 (f(i) = i + (i>>4)) -> odd stride 17
// keeps all transpose gathers at <=2-3 way bank aliasing (2-way is free).
__global__ __launch_bounds__(256) void fwht_kernel(const float* __restrict__ x,
                                                   const float* __restrict__ signs,
                                                   float* __restrict__ out) {
    __shared__ float lds[4352];  // 4096 + 256 pad floats = 17 KB

    const int t = threadIdx.x;
    const long row = blockIdx.x;
    const float* __restrict__ xr = x + row * (long)D;
    float* __restrict__ orow = out + row * (long)D;

    float v[16];

    // ---- P1: coalesced float4 load (16 B/lane), apply signs, H16 over b ----
    {
        const float4* __restrict__ xv = (const float4*)(xr + t * 16);
        const float4* __restrict__ sv = (const float4*)(signs + t * 16);
#pragma unroll
        for (int k = 0; k < 4; k++) {
            float4 a = xv[k];
            float4 s = sv[k];
            v[4 * k + 0] = a.x * s.x;
            v[4 * k + 1] = a.y * s.y;
            v[4 * k + 2] = a.z * s.z;
            v[4 * k + 3] = a.w * s.w;
        }
    }
    fwht16(v);

    // contiguous padded write: element i = 16t + b -> f = 17t + b
#pragma unroll
    for (int b = 0; b < 16; b++) lds[17 * t + b] = v[b];
    __syncthreads();

    // ---- P2: thread (a2 = t>>4, b = t&15) gathers over a1 (stride 17) ----
    {
        const int a2 = t >> 4, b = t & 15;
        const int base = a2 * 272 + b;  // f = a2*272 + a1*17 + b
#pragma unroll
        for (int a1 = 0; a1 < 16; a1++) v[a1] = lds[base + a1 * 17];
        fwht16(v);
#pragma unroll
        for (int a1 = 0; a1 < 16; a1++) lds[base + a1 * 17] = v[a1];
    }
    __syncthreads();

    // ---- P3: thread (a1 = t>>4, b = t&15) gathers over a2 (stride 272) ----
    {
        const int base = (t >> 4) * 17 + (t & 15);  // a1*17 + b
#pragma unroll
        for (int a2 = 0; a2 < 16; a2++) v[a2] = lds[base + a2 * 272];
        fwht16(v);
        const float scale = 1.0f / 64.0f;  // 4096^-0.5
        // element index = a2*256 + a1*16 + b = a2*256 + t:
        // each store instruction is a contiguous 256 B coalesced wave write.
#pragma unroll
        for (int a2 = 0; a2 < 16; a2++) orow[a2 * 256 + t] = v[a2] * scale;
    }
}

extern "C" void kernel_launch(void* const* d_in, const int* in_sizes, int n_in,
                              void* d_out, int out_size, void* d_ws, size_t ws_size,
                              hipStream_t stream) {
    const float* x = (const float*)d_in[0];
    const float* signs = (const float*)d_in[1];
    float* out = (float*)d_out;
    const int rows = in_sizes[0] / D;  // 8192
    fwht_kernel<<<dim3(rows), dim3(256), 0, stream>>>(x, signs, out);
}